// Round 14
// baseline (679.125 us; speedup 1.0000x reference)
//
#include <hip/hip_runtime.h>
#include <hip/hip_bf16.h>
#include <math.h>

#define BB 8
#define LL 2048
#define LQ 512             // quarter sequence (recurrence runs in 4 passes)
#define DD 128

// ---------------------------------------------------------------------------
// DPP helpers: full-rate VALU cross-lane adds (no LDS in the serial chain).
// ---------------------------------------------------------------------------
template <int CTRL>
__device__ __forceinline__ float dpp_add(float x) {
    int xi = __float_as_int(x);
    int yi = __builtin_amdgcn_update_dpp(xi, xi, CTRL, 0xF, 0xF, false);
    return x + __int_as_float(yi);
}
// 16-lane allreduce: ^1, ^2 (quad_perm), ^:8 (half_mirror), ^:16 (mirror)
__device__ __forceinline__ float allreduce16(float p) {
    p = dpp_add<0xB1>(p);
    p = dpp_add<0x4E>(p);
    p = dpp_add<0x141>(p);
    p = dpp_add<0x140>(p);
    return p;
}
__device__ __forceinline__ float rlane(float p, int l) {
    return __int_as_float(__builtin_amdgcn_readlane(__float_as_int(p), l));
}
// async global->LDS DMA, 16 B/lane: LDS dest = uniform base + lane*16.
__device__ __forceinline__ void dma16(const float* g, char* l) {
    __builtin_amdgcn_global_load_lds(
        (const __attribute__((address_space(1))) void*)g,
        (__attribute__((address_space(3))) void*)l, 16, 0, 0);
}

// ---------------------------------------------------------------------------
// C[M,O] = X @ W[O,128]^T, optional sigmoid. X rows addressed with (batch,
// quarter) strides: row m -> b=m>>11, t=m&2047, q=t>>9, tl=t&511;
// addr = X + b*sB + q*sQ + tl*ldx.    (proven R12)
// ---------------------------------------------------------------------------
__global__ __launch_bounds__(256) void gemm_kernel(
    const float* __restrict__ X, long ldx, long sB, long sQ,
    const float* __restrict__ W,
    float* __restrict__ C, int ldc,
    int applySig)
{
    __shared__ float Xs[32 * 132];
    __shared__ float Ws[64 * 132];
    const int tid = threadIdx.x;
    const int m0 = blockIdx.x * 32;
    const int o0 = blockIdx.y * 64;
    {
        int row = tid >> 3, cg = tid & 7;
        int m = m0 + row;
        int b = m >> 11, t = m & 2047, qq = t >> 9, tl = t & 511;
        const float* src = X + (size_t)b * sB + (size_t)qq * sQ
                             + (size_t)tl * ldx + cg * 16;
        float* dst = Xs + row * 132 + cg * 16;
#pragma unroll
        for (int u = 0; u < 4; ++u)
            *(float4*)(dst + 4 * u) = *(const float4*)(src + 4 * u);
    }
    {
        int o = tid >> 2, cg = tid & 3;
        const float* src = W + (size_t)(o0 + o) * 128 + cg * 32;
        float* dst = Ws + o * 132 + cg * 32;
#pragma unroll
        for (int u = 0; u < 8; ++u)
            *(float4*)(dst + 4 * u) = *(const float4*)(src + 4 * u);
    }
    __syncthreads();
    const int tx = tid & 31, ty = tid >> 5;
    float acc[4][2] = {};
    const float* xb = Xs + (ty * 4) * 132;
    const float* wb = Ws + (tx * 2) * 132;
    for (int k0 = 0; k0 < 128; k0 += 4) {
        float4 xr[4], wr[2];
#pragma unroll
        for (int r = 0; r < 4; ++r) xr[r] = *(const float4*)(xb + r * 132 + k0);
#pragma unroll
        for (int cc = 0; cc < 2; ++cc) wr[cc] = *(const float4*)(wb + cc * 132 + k0);
#pragma unroll
        for (int r = 0; r < 4; ++r)
#pragma unroll
            for (int cc = 0; cc < 2; ++cc) {
                acc[r][cc] += xr[r].x * wr[cc].x + xr[r].y * wr[cc].y
                            + xr[r].z * wr[cc].z + xr[r].w * wr[cc].w;
            }
    }
#pragma unroll
    for (int r = 0; r < 4; ++r)
#pragma unroll
        for (int cc = 0; cc < 2; ++cc) {
            float v = acc[r][cc];
            if (applySig) v = 1.0f / (1.0f + __expf(-v));
            C[(size_t)(m0 + ty * 4 + r) * ldc + o0 + tx * 2 + cc] = v;
        }
}

// ---------------------------------------------------------------------------
// Depthwise conv(K=3) + sigmoid + L2-norm for q,k; packs the recurrence
// stream TIME-BLOCKED (TB=4): for batch b, block tb=t>>2, ti=t&3:
//   pack2[(b*512 + tb)*2560 + (o*128 + d)*4 + ti],  o in {k,m,a,q,v}
// ---------------------------------------------------------------------------
__global__ __launch_bounds__(256) void convnorm_kernel(
    const float* __restrict__ qkv,
    const float* __restrict__ qw, const float* __restrict__ qb,
    const float* __restrict__ kw, const float* __restrict__ kb,
    const float* __restrict__ ab,
    float* __restrict__ pack)
{
    const int tid = threadIdx.x;
    const int lane = tid & 63;
    const int wid = tid >> 6;
    const int m = blockIdx.x * 4 + wid;     // b*L + l
    const int l = m & (LL - 1);
    const int b = m >> 11;
    const int d0 = lane * 2;
    float yq0 = qb[d0], yq1 = qb[d0 + 1];
    float yk0 = kb[d0], yk1 = kb[d0 + 1];
#pragma unroll
    for (int tau = 0; tau < 3; ++tau) {
        int lp = l + tau - 1;
        if (lp >= 0 && lp < LL) {
            const float* base = qkv + (size_t)(m + tau - 1) * 512;
            yq0 += base[d0]       * qw[d0 * 3 + tau];
            yq1 += base[d0 + 1]   * qw[(d0 + 1) * 3 + tau];
            yk0 += base[128 + d0]     * kw[d0 * 3 + tau];
            yk1 += base[128 + d0 + 1] * kw[(d0 + 1) * 3 + tau];
        }
    }
    yq0 = 1.0f / (1.0f + __expf(-yq0));
    yq1 = 1.0f / (1.0f + __expf(-yq1));
    yk0 = 1.0f / (1.0f + __expf(-yk0));
    yk1 = 1.0f / (1.0f + __expf(-yk1));
    float sq = yq0 * yq0 + yq1 * yq1;
    float sk = yk0 * yk0 + yk1 * yk1;
#pragma unroll
    for (int msk = 1; msk <= 32; msk <<= 1) {
        sq += __shfl_xor(sq, msk);
        sk += __shfl_xor(sk, msk);
    }
    float rq = 1.0f / fmaxf(sqrtf(sq), 1e-12f);
    float rk = 1.0f / fmaxf(sqrtf(sk), 1e-12f);
    float k0n = yk0 * rk, k1n = yk1 * rk;
    float a0 = ab[(size_t)m * 256 + d0];
    float a1 = ab[(size_t)m * 256 + d0 + 1];
    float b0 = ab[(size_t)m * 256 + 128 + d0];
    float b1 = ab[(size_t)m * 256 + 128 + d0 + 1];
    float v0 = qkv[(size_t)m * 512 + 256 + d0];
    float v1 = qkv[(size_t)m * 512 + 256 + d0 + 1];
    float* P = pack + ((size_t)b * 512 + (l >> 2)) * 2560 + (l & 3);
    P[d0 * 4]              = k0n;      P[(d0 + 1) * 4]        = k1n;
    P[512 + d0 * 4]        = b0 * k0n; P[512 + (d0 + 1) * 4]  = b1 * k1n;
    P[1024 + d0 * 4]       = a0;       P[1024 + (d0 + 1) * 4] = a1;
    P[1536 + d0 * 4]       = yq0 * rq; P[1536 + (d0 + 1) * 4] = yq1 * rq;
    P[2048 + d0 * 4]       = v0;       P[2048 + (d0 + 1) * 4] = v1;
}

// ---------------------------------------------------------------------------
// Barrier-free delta-rule recurrence, R=1 row/wave, QUARTER sequence/call.
// Grid 1024 = BB*128 one-wave WGs. R12/R13 lesson: VGPR block-double-buffer
// keeps collapsing (VGPR=40/44) -> each block exposes the full L3/HBM miss
// latency that all ~16 same-batch waves/XCD pay simultaneously (~1000 cyc).
// Fix: LDS ring (depth 3 x 8 KB) filled by global_load_lds DMA (no VGPR
// pressure -> nothing to collapse), prefetch distance 2 blocks (~covers
// HBM latency), consumption via ds_read_b128, synchronization by MANUAL
// s_waitcnt vmcnt(N):  FIFO count at block-n top: younger = stores(n-2)=4
// + DMA(n+1)=8 => vmcnt(12) guarantees DMA(n) landed (tb=0: vmcnt(8)).
// sched_barrier(0) fences pin [wait][reads][DMA][compute] section order so
// reads can't hoist above the wait or sink into the next iteration (WAW
// with the buffer being re-filled at distance 3).
// LDS buffer layout (byte offsets): k lo/hi [0,2K), m [2K,4K), a [4K,6K),
// q dup [6K,7K), v dup [7K,8K); lane l's slot = region + l*16.
// Per step (R12-proven math): dot(2) -> allreduce16 -> 4 rlane + 3 add ->
// 2x(3-op update) -> 2 mul -> packed bf16 store.
// ---------------------------------------------------------------------------
__global__ __launch_bounds__(64) void recur1_kernel(
    const float* __restrict__ pack, const float* __restrict__ sin,
    __hip_bfloat16* __restrict__ pout, float* __restrict__ sout, int blk0)
{
    __shared__ __attribute__((aligned(16))) char smem[3 * 8192];
    const int lane = threadIdx.x;
    const int b = blockIdx.x >> 7;
    const int g = blockIdx.x & 127;
    const int j0 = lane * 2;

    float SA[2];
    {
        const float* sp = sin + ((size_t)b * DD + g) * DD + j0;
        float2 t2 = *(const float2*)sp;
        SA[0] = t2.x; SA[1] = t2.y;
    }

    const float* P0 = pack + ((size_t)b * 512 + blk0) * 2560;
    __hip_bfloat16* po = pout + ((size_t)g * (BB * LQ) + (size_t)b * LQ) * DD + j0;

#define DMABLK(BUF, OFF)                                                     \
    do {                                                                     \
        char* L = smem + (BUF) * 8192;                                       \
        const float* G = P0 + (size_t)(OFF) * 2560;                          \
        dma16(G + lane * 8,              L + 0);                             \
        dma16(G + lane * 8 + 4,          L + 1024);                          \
        dma16(G + 512 + lane * 8,        L + 2048);                          \
        dma16(G + 512 + lane * 8 + 4,    L + 3072);                          \
        dma16(G + 1024 + lane * 8,       L + 4096);                          \
        dma16(G + 1024 + lane * 8 + 4,   L + 5120);                          \
        dma16(G + 1536 + g * 4,          L + 6144);                          \
        dma16(G + 2048 + g * 4,          L + 7168);                          \
    } while (0)

#define STEPQ(CMP)                                                           \
    do {                                                                     \
        float e = SA[0] * k_lo.CMP;                                          \
        e = fmaf(SA[1], k_hi.CMP, e);                                        \
        float p = allreduce16(e);                                            \
        float sk = (rlane(p, 0) + rlane(p, 16))                              \
                 + (rlane(p, 32) + rlane(p, 48));                            \
        float vg = v4.CMP, qg = q4.CMP;                                      \
        float a0 = a_lo.CMP, a1 = a_hi.CMP;                                  \
        float w0 = fmaf(-a0, sk, vg);                                        \
        SA[0] = fmaf(m_lo.CMP, w0, a0 * SA[0]);                              \
        float w1 = fmaf(-a1, sk, vg);                                        \
        SA[1] = fmaf(m_hi.CMP, w1, a1 * SA[1]);                              \
        __hip_bfloat162 h2;                                                  \
        h2.x = __float2bfloat16(qg * SA[0]);                                 \
        h2.y = __float2bfloat16(qg * SA[1]);                                 \
        *(__hip_bfloat162*)po = h2;                                          \
        po += DD;                                                            \
    } while (0)

    DMABLK(0, 0);    // block 0 -> buf 0
    DMABLK(1, 1);    // block 1 -> buf 1

    for (int tb = 0; tb < LQ / 4; ++tb) {
        // wait for this block's DMA (FIFO-counted; see header comment)
        if (tb == 0) __builtin_amdgcn_s_waitcnt(0x0F78);   // vmcnt(8)
        else         __builtin_amdgcn_s_waitcnt(0x0F7C);   // vmcnt(12)
        __builtin_amdgcn_sched_barrier(0);
        const char* Lc = smem + (tb % 3) * 8192;
        float4 k_lo = *(const float4*)(Lc + lane * 16);
        float4 k_hi = *(const float4*)(Lc + 1024 + lane * 16);
        float4 m_lo = *(const float4*)(Lc + 2048 + lane * 16);
        float4 m_hi = *(const float4*)(Lc + 3072 + lane * 16);
        float4 a_lo = *(const float4*)(Lc + 4096 + lane * 16);
        float4 a_hi = *(const float4*)(Lc + 5120 + lane * 16);
        float4 q4   = *(const float4*)(Lc + 6144 + lane * 16);
        float4 v4   = *(const float4*)(Lc + 7168 + lane * 16);
        __builtin_amdgcn_sched_barrier(0);
        // prefetch block tb+2 (tail overruns into ws beyond pack: unused)
        DMABLK((tb + 2) % 3, tb + 2);
        __builtin_amdgcn_sched_barrier(0);
        STEPQ(x); STEPQ(y); STEPQ(z); STEPQ(w);
        __builtin_amdgcn_sched_barrier(0);
    }
#undef DMABLK
#undef STEPQ

    {
        float* sp = sout + ((size_t)b * DD + g) * DD + j0;
        float2 o2 = {SA[0], SA[1]};
        *(float2*)sp = o2;
    }
}

// ---------------------------------------------------------------------------
// oc(quarter) = silu(sum_{g<128} pout[g])  bf16 -> fp32. Writes into the
// DEAD quarter-band of pack:
//   oc(b,q,tl,d) = ocbase[b*512*2560 + q*128*2560 + tl*128 + d]   (proven R12)
// ---------------------------------------------------------------------------
__global__ __launch_bounds__(256) void combine_silu_kernel(
    const ushort* __restrict__ pout, float* __restrict__ ocbase, int q)
{
    const size_t NQ = (size_t)BB * LQ * DD;   // 524288 elems per slice
    size_t idx = ((size_t)blockIdx.x * 256 + threadIdx.x) * 4;
    float s0 = 0, s1 = 0, s2 = 0, s3 = 0;
#pragma unroll 8
    for (int gi = 0; gi < 128; ++gi) {
        uint2 u = *(const uint2*)(pout + gi * NQ + idx);
        s0 += __uint_as_float((u.x & 0xffffu) << 16);
        s1 += __uint_as_float(u.x & 0xffff0000u);
        s2 += __uint_as_float((u.y & 0xffffu) << 16);
        s3 += __uint_as_float(u.y & 0xffff0000u);
    }
    float4 r;
    r.x = s0 / (1.0f + __expf(-s0));
    r.y = s1 / (1.0f + __expf(-s1));
    r.z = s2 / (1.0f + __expf(-s2));
    r.w = s3 / (1.0f + __expf(-s3));
    size_t b = idx >> 16;                 // / (LQ*DD)
    size_t rem = idx & ((size_t)LQ * DD - 1);
    float* dst = ocbase + b * (512ull * 2560) + (size_t)q * (128ull * 2560) + rem;
    *(float4*)dst = r;
}

// ---------------------------------------------------------------------------
// d_out = y * rsqrt(mean(y^2)+1e-6) * rms_w + residual. One wave per (b,l).
// ---------------------------------------------------------------------------
__global__ __launch_bounds__(256) void rms_res_kernel(
    const float* __restrict__ y, const float* __restrict__ res,
    const float* __restrict__ rmsw, float* __restrict__ out)
{
    const int tid = threadIdx.x;
    const int lane = tid & 63;
    const int wid = tid >> 6;
    const int m = blockIdx.x * 4 + wid;
    const int d0 = lane * 2;
    size_t o = (size_t)m * DD + d0;
    float2 yv = *(const float2*)(y + o);
    float ss = yv.x * yv.x + yv.y * yv.y;
#pragma unroll
    for (int msk = 1; msk <= 32; msk <<= 1) ss += __shfl_xor(ss, msk);
    float r = rsqrtf(ss * (1.0f / 128.0f) + 1e-6f);
    float2 rv = *(const float2*)(res + o);
    out[o]     = yv.x * r * rmsw[d0]     + rv.x;
    out[o + 1] = yv.y * r * rmsw[d0 + 1] + rv.y;
}

// ---------------------------------------------------------------------------
// Workspace (176,160,768 B total — the R7..R13-proven footprint):
//   [0, 41.9MB)   pack2 blocked [B,512,2560] fp32. After each quarter's
//                 recurrence that quarter's band is dead -> combine -> oc.
//   [41.9MB, +134.2MB) poreg:
//      phase 1:  qkv [M,512] + abv [M,256]
//      phase 2:  pout bf16, 128 slices x [B,LQ,D]  (reused for 4 quarters)
//      phase 3:  res [M,128] + yb [M,128]
// Inter-pass state lives in sfin (inside d_out): written pass q, read q+1.
// ---------------------------------------------------------------------------
extern "C" void kernel_launch(void* const* d_in, const int* in_sizes, int n_in,
                              void* d_out, int out_size, void* d_ws, size_t ws_size,
                              hipStream_t stream)
{
    const float* x      = (const float*)d_in[0];
    const float* state  = (const float*)d_in[1];
    const float* W_in   = (const float*)d_in[2];
    const float* W_gate = (const float*)d_in[3];
    const float* W_out  = (const float*)d_in[4];
    const float* W_res  = (const float*)d_in[5];
    const float* qcw    = (const float*)d_in[6];
    const float* qcb    = (const float*)d_in[7];
    const float* kcw    = (const float*)d_in[8];
    const float* kcb    = (const float*)d_in[9];
    const float* rmsw   = (const float*)d_in[10];
    float* out  = (float*)d_out;
    float* sfin = out + (size_t)BB * LL * DD;

    const size_t M = (size_t)BB * LL;            // 16384
    char* base = (char*)d_ws;
    const size_t PACK_BYTES = M * 640 * 4;       // 41.9 MB
    float* pack = (float*)base;
    char*  poreg = base + PACK_BYTES;
    float* qkv = (float*)poreg;                              // phase 1
    float* abv = (float*)(poreg + M * 512 * 4);              // phase 1
    __hip_bfloat16* po = (__hip_bfloat16*)poreg;             // phase 2
    float* res = (float*)poreg;                              // phase 3 (over po)
    float* yb  = (float*)(poreg + M * DD * 4);               // phase 3

    dim3 blk(256);
    // qkv = x @ W_in^T  [M,512]
    gemm_kernel<<<dim3(M / 32, 8), blk, 0, stream>>>(
        x, 128, 2048L * 128, 512L * 128, W_in, qkv, 512, 0);
    // alpha/beta = sigmoid(gate @ W_gate^T) [M,256]
    gemm_kernel<<<dim3(M / 32, 4), blk, 0, stream>>>(
        qkv + 384, 512, 2048L * 512, 512L * 512, W_gate, abv, 256, 1);
    // conv + sigmoid + l2norm + blocked pack stream [k|m|alpha|q|v] x TB=4
    convnorm_kernel<<<dim3(M / 4), blk, 0, stream>>>(qkv, qcw, qcb, kcw, kcb, abv, pack);
    // recurrence in 4 quarter passes; state relayed through sfin
    for (int q = 0; q < 4; ++q) {
        const float* sin = (q == 0) ? state : sfin;
        recur1_kernel<<<dim3(BB * 128), dim3(64), 0, stream>>>(
            pack, sin, po, sfin, q * 128);
        combine_silu_kernel<<<dim3(512), blk, 0, stream>>>(
            (const ushort*)po, pack, q);
    }
    // residual = x @ W_res^T  (po region dead after last combine)
    gemm_kernel<<<dim3(M / 32, 2), blk, 0, stream>>>(
        x, 128, 2048L * 128, 512L * 128, W_res, res, 128, 0);
    // y = oc @ W_out^T   (oc scattered in pack: sB=512*2560, sQ=128*2560)
    gemm_kernel<<<dim3(M / 32, 2), blk, 0, stream>>>(
        pack, 128, 512L * 2560, 128L * 2560, W_out, yb, 128, 0);
    // RMS + residual -> d_out
    rms_res_kernel<<<dim3(M / 4), blk, 0, stream>>>(yb, res, rmsw, out);
}